// Round 1
// baseline (6263.914 us; speedup 1.0000x reference)
//
#include <hip/hip_runtime.h>

constexpr int Nn = 100000;
constexpr int Ne = 1600000;
constexpr float BN_EPS = 1e-5f;

// ---------- small utility kernels ----------

__global__ void fill_kernel(float* __restrict__ p, float v, int n) {
  int i = blockIdx.x * blockDim.x + threadIdx.x;
  if (i < n) p[i] = v;
}

__global__ void deg_accum_kernel(const int* __restrict__ row,
                                 const float* __restrict__ w,
                                 float* __restrict__ deg) {
  int e = blockIdx.x * blockDim.x + threadIdx.x;
  if (e < Ne) atomicAdd(&deg[row[e]], w[e]);
}

__global__ void dinv_kernel(float* __restrict__ d) {
  int i = blockIdx.x * blockDim.x + threadIdx.x;
  if (i < Nn) {
    float v = d[i];
    d[i] = (v > 0.f) ? rsqrtf(fmaxf(v, 1e-12f)) : 0.f;
  }
}

__global__ void norm_kernel(const int* __restrict__ row, const int* __restrict__ col,
                            const float* __restrict__ w, const float* __restrict__ dinv,
                            float* __restrict__ nrm) {
  int e = blockIdx.x * blockDim.x + threadIdx.x;
  if (e < Ne) nrm[e] = dinv[row[e]] * w[e] * dinv[col[e]];
}

// ---------- FP32 tiled GEMM: C[M,Nc] = A[M,K] @ W[K,Nc] (+bias)(relu) ----------
// K is always a multiple of 16; Nc a multiple of 4. 64x64 tile, 4x4 per thread.

__global__ __launch_bounds__(256)
void gemm_kernel(const float* __restrict__ A, const float* __restrict__ W,
                 const float* __restrict__ bias, float* __restrict__ C,
                 int M, int K, int Nc, int relu) {
  constexpr int BM = 64, BN = 64, BK = 16;
  __shared__ float As[BK][BM + 4];  // +4 pad keeps 16B alignment for float4 reads
  __shared__ float Ws[BK][BN];
  int t = threadIdx.x;
  int tx = t & 15, ty = t >> 4;
  int row0 = blockIdx.y * BM, col0 = blockIdx.x * BN;
  float acc[4][4] = {};
  for (int k0 = 0; k0 < K; k0 += BK) {
    {
      int r = t >> 2;            // 0..63
      int kq = (t & 3) << 2;     // 0,4,8,12
      int grow = row0 + r;
      float4 a = make_float4(0.f, 0.f, 0.f, 0.f);
      if (grow < M) a = *(const float4*)(A + (size_t)grow * K + (k0 + kq));
      As[kq + 0][r] = a.x; As[kq + 1][r] = a.y;
      As[kq + 2][r] = a.z; As[kq + 3][r] = a.w;
    }
    {
      int r = t >> 4;            // 0..15
      int c = (t & 15) << 2;     // 0..60
      int gc = col0 + c;
      float4 w4 = make_float4(0.f, 0.f, 0.f, 0.f);
      if (gc < Nc) w4 = *(const float4*)(W + (size_t)(k0 + r) * Nc + gc);
      Ws[r][c + 0] = w4.x; Ws[r][c + 1] = w4.y;
      Ws[r][c + 2] = w4.z; Ws[r][c + 3] = w4.w;
    }
    __syncthreads();
#pragma unroll
    for (int kk = 0; kk < BK; kk++) {
      float4 av = *(const float4*)&As[kk][ty << 2];
      float4 wv = *(const float4*)&Ws[kk][tx << 2];
      float a4[4] = {av.x, av.y, av.z, av.w};
      float w4[4] = {wv.x, wv.y, wv.z, wv.w};
#pragma unroll
      for (int i = 0; i < 4; i++)
#pragma unroll
        for (int j = 0; j < 4; j++)
          acc[i][j] += a4[i] * w4[j];
    }
    __syncthreads();
  }
#pragma unroll
  for (int i = 0; i < 4; i++) {
    int grow = row0 + (ty << 2) + i;
    if (grow >= M) continue;
#pragma unroll
    for (int j = 0; j < 4; j++) {
      int gc = col0 + (tx << 2) + j;
      if (gc >= Nc) continue;
      float v = acc[i][j];
      if (bias) v += bias[gc];
      if (relu) v = fmaxf(v, 0.f);
      C[(size_t)grow * Nc + gc] = v;
    }
  }
}

// ---------- SpMM pieces ----------
// out[i,:] = dinv[i]^2 * t[i,:]  (self-loop term initializes the accumulator)
__global__ void selfloop_init_kernel(const float* __restrict__ t, const float* __restrict__ dinv,
                                     float* __restrict__ out, int total4, int shift) {
  int g = blockIdx.x * blockDim.x + threadIdx.x;
  if (g >= total4) return;
  int node = g >> shift;
  float s = dinv[node]; s *= s;
  float4 v = ((const float4*)t)[g];
  ((float4*)out)[g] = make_float4(s * v.x, s * v.y, s * v.z, s * v.w);
}

// out[row[e],:] += norm[e] * t[col[e],:]
__global__ void scatter_kernel(const float* __restrict__ t, const int* __restrict__ row,
                               const int* __restrict__ col, const float* __restrict__ nrm,
                               float* __restrict__ out, int shift, int D) {
  int g = blockIdx.x * blockDim.x + threadIdx.x;
  if (g >= (Ne << shift)) return;
  int e = g >> shift;
  int j = g & ((1 << shift) - 1);
  int r = row[e], c = col[e];
  float nm = nrm[e];
  float4 v = ((const float4*)(t + (size_t)c * D))[j];
  float* o = out + (size_t)r * D + (j << 2);
  atomicAdd(o + 0, nm * v.x);
  atomicAdd(o + 1, nm * v.y);
  atomicAdd(o + 2, nm * v.z);
  atomicAdd(o + 3, nm * v.w);
}

__global__ void bias_act_kernel(float* __restrict__ x, const float* __restrict__ b,
                                int total4, int jmask, int relu) {
  int g = blockIdx.x * blockDim.x + threadIdx.x;
  if (g >= total4) return;
  int j = g & jmask;
  float4 v = ((float4*)x)[g];
  float4 bb = ((const float4*)b)[j];
  v.x += bb.x; v.y += bb.y; v.z += bb.z; v.w += bb.w;
  if (relu) {
    v.x = fmaxf(v.x, 0.f); v.y = fmaxf(v.y, 0.f);
    v.z = fmaxf(v.z, 0.f); v.w = fmaxf(v.w, 0.f);
  }
  ((float4*)x)[g] = v;
}

// ---------- BatchNorm (training-mode batch stats, biased variance) ----------
// stats[0:C] = sum, stats[C:2C] = sumsq  (must be pre-zeroed)
__global__ __launch_bounds__(256)
void bn_stats_kernel(const float* __restrict__ x, float* __restrict__ stats, int C) {
  __shared__ float ss[256], sq[256];
  int tid = threadIdx.x;
  int col = tid & (C - 1);
  int rgrp = tid / C;
  int rpb = 256 / C;
  float s = 0.f, q = 0.f;
  for (int r = blockIdx.x * rpb + rgrp; r < Nn; r += gridDim.x * rpb) {
    float v = x[(size_t)r * C + col];
    s += v; q += v * v;
  }
  ss[tid] = s; sq[tid] = q;
  __syncthreads();
  for (int st = 128; st >= C; st >>= 1) {
    if (tid < st) { ss[tid] += ss[tid + st]; sq[tid] += sq[tid + st]; }
    __syncthreads();
  }
  if (tid < C) {
    atomicAdd(&stats[tid], ss[tid]);
    atomicAdd(&stats[C + tid], sq[tid]);
  }
}

__global__ void bn_apply_kernel(float* __restrict__ x, float* __restrict__ dup,
                                const float* __restrict__ stats,
                                const float* __restrict__ g, const float* __restrict__ beta,
                                int total, int cmask, int C) {
  int i = blockIdx.x * blockDim.x + threadIdx.x;
  if (i >= total) return;
  int c = i & cmask;
  float m = stats[c] * (1.f / Nn);
  float var = stats[C + c] * (1.f / Nn) - m * m;
  float v = (x[i] - m) * rsqrtf(var + BN_EPS) * g[c] + beta[c];
  x[i] = v;
  if (dup) dup[i] = v;
}

// ---------- Student-t cluster assignment ----------
__global__ __launch_bounds__(256)
void q_kernel(const float* __restrict__ z, const float* __restrict__ centers,
              float* __restrict__ q) {
  __shared__ float cs[50 * 32];
  __shared__ float cn[50];
  int tid = threadIdx.x;
  for (int i = tid; i < 50 * 32; i += 256) cs[i] = centers[i];
  __syncthreads();
  if (tid < 50) {
    float s = 0.f;
    for (int j = 0; j < 32; j++) { float v = cs[tid * 32 + j]; s += v * v; }
    cn[tid] = s;
  }
  __syncthreads();
  int n = blockIdx.x * blockDim.x + tid;
  if (n >= Nn) return;
  float zr[32];
  float zn = 0.f;
  const float4* zp = (const float4*)(z + (size_t)n * 32);
#pragma unroll
  for (int j = 0; j < 8; j++) {
    float4 v = zp[j];
    zr[j * 4 + 0] = v.x; zr[j * 4 + 1] = v.y;
    zr[j * 4 + 2] = v.z; zr[j * 4 + 3] = v.w;
    zn += v.x * v.x + v.y * v.y + v.z * v.z + v.w * v.w;
  }
  float qv[50];
  float qs = 0.f;
  for (int k = 0; k < 50; k++) {
    float dot = 0.f;
#pragma unroll
    for (int j = 0; j < 32; j++) dot += zr[j] * cs[k * 32 + j];
    float d2 = zn + cn[k] - 2.f * dot;
    d2 = fmaxf(d2, 0.f);
    float qq = 1.f / (1.f + d2);
    qv[k] = qq; qs += qq;
  }
  float inv = 1.f / qs;
  float* qo = q + (size_t)n * 50;
  for (int k = 0; k < 50; k++) qo[k] = qv[k] * inv;
}

// ---------- launch ----------

extern "C" void kernel_launch(void* const* d_in, const int* in_sizes, int n_in,
                              void* d_out, int out_size, void* d_ws, size_t ws_size,
                              hipStream_t stream) {
  const float* x     = (const float*)d_in[0];
  const int*   ei    = (const int*)d_in[1];
  const float* ew    = (const float*)d_in[2];
  const float* W_g1  = (const float*)d_in[3];
  const float* b_g1  = (const float*)d_in[4];
  const float* W_g2  = (const float*)d_in[5];
  const float* b_g2  = (const float*)d_in[6];
  const float* W_g3  = (const float*)d_in[7];
  const float* b_g3  = (const float*)d_in[8];
  const float* W_mu  = (const float*)d_in[9];
  const float* b_mu  = (const float*)d_in[10];
  const float* W_lv  = (const float*)d_in[11];
  const float* b_lv  = (const float*)d_in[12];
  const float* g_mu  = (const float*)d_in[13];
  const float* be_mu = (const float*)d_in[14];
  const float* g_lv  = (const float*)d_in[15];
  const float* be_lv = (const float*)d_in[16];
  const float* W_d1  = (const float*)d_in[17];
  const float* b_d1  = (const float*)d_in[18];
  const float* g_d1  = (const float*)d_in[19];
  const float* be_d1 = (const float*)d_in[20];
  const float* W_d2  = (const float*)d_in[21];
  const float* b_d2  = (const float*)d_in[22];
  const float* g_d2  = (const float*)d_in[23];
  const float* be_d2 = (const float*)d_in[24];
  const float* W_d3  = (const float*)d_in[25];
  const float* b_d3  = (const float*)d_in[26];
  const float* cent  = (const float*)d_in[27];

  const int* row = ei;        // edge_index[0]
  const int* col = ei + Ne;   // edge_index[1]

  float* out    = (float*)d_out;
  float* out_z  = out;
  float* out_mu = out + (size_t)Nn * 32;
  float* out_lv = out + (size_t)Nn * 64;
  float* out_xr = out + (size_t)Nn * 96;   // [N,256]
  float* out_q  = out + (size_t)Nn * 352;  // [N,50]

  // workspace: dinv[N] | norm[E] | bufB[N*128] | stats[512]  (~58 MB)
  float* ws    = (float*)d_ws;
  float* dinv  = ws;
  float* nrm   = dinv + Nn;
  float* bufB  = nrm + Ne;
  float* stats = bufB + (size_t)Nn * 128;
  float* st_mu = stats, *st_lv = stats + 64, *st_d1 = stats + 128, *st_d2 = stats + 256;

  // scratch inside the x_recon output region (written last, so safe):
  float* bufA = out_xr;                     // [N,128]
  float* bufC = out_xr + (size_t)Nn * 128;  // [N,64]
  float* bufD = out_xr + (size_t)Nn * 192;  // [N,64]

  auto cdiv = [](long a, long b) { return (int)((a + b - 1) / b); };
  dim3 blk(256);

  // degree / dinv / edge norms
  fill_kernel<<<cdiv(Nn, 256), blk, 0, stream>>>(dinv, 1.0f, Nn);  // self-loop weight
  deg_accum_kernel<<<cdiv(Ne, 256), blk, 0, stream>>>(row, ew, dinv);
  dinv_kernel<<<cdiv(Nn, 256), blk, 0, stream>>>(dinv);
  norm_kernel<<<cdiv(Ne, 256), blk, 0, stream>>>(row, col, ew, dinv, nrm);
  fill_kernel<<<cdiv(512, 256), blk, 0, stream>>>(stats, 0.f, 512);

  // GCN layer 1: 256 -> 128, relu
  gemm_kernel<<<dim3(2, cdiv(Nn, 64)), blk, 0, stream>>>(x, W_g1, nullptr, bufA, Nn, 256, 128, 0);
  selfloop_init_kernel<<<cdiv((long)Nn * 32, 256), blk, 0, stream>>>(bufA, dinv, bufB, Nn * 32, 5);
  scatter_kernel<<<cdiv((long)Ne * 32, 256), blk, 0, stream>>>(bufA, row, col, nrm, bufB, 5, 128);
  bias_act_kernel<<<cdiv((long)Nn * 32, 256), blk, 0, stream>>>(bufB, b_g1, Nn * 32, 31, 1);

  // GCN layer 2: 128 -> 64, relu
  gemm_kernel<<<dim3(1, cdiv(Nn, 64)), blk, 0, stream>>>(bufB, W_g2, nullptr, bufC, Nn, 128, 64, 0);
  selfloop_init_kernel<<<cdiv((long)Nn * 16, 256), blk, 0, stream>>>(bufC, dinv, bufD, Nn * 16, 4);
  scatter_kernel<<<cdiv((long)Ne * 16, 256), blk, 0, stream>>>(bufC, row, col, nrm, bufD, 4, 64);
  bias_act_kernel<<<cdiv((long)Nn * 16, 256), blk, 0, stream>>>(bufD, b_g2, Nn * 16, 15, 1);

  // GCN layer 3: 64 -> 64, no relu
  gemm_kernel<<<dim3(1, cdiv(Nn, 64)), blk, 0, stream>>>(bufD, W_g3, nullptr, bufA, Nn, 64, 64, 0);
  selfloop_init_kernel<<<cdiv((long)Nn * 16, 256), blk, 0, stream>>>(bufA, dinv, bufC, Nn * 16, 4);
  scatter_kernel<<<cdiv((long)Ne * 16, 256), blk, 0, stream>>>(bufA, row, col, nrm, bufC, 4, 64);
  bias_act_kernel<<<cdiv((long)Nn * 16, 256), blk, 0, stream>>>(bufC, b_g3, Nn * 16, 15, 0);

  // VAE heads: 64 -> 32 (+BN); z = mu
  gemm_kernel<<<dim3(1, cdiv(Nn, 64)), blk, 0, stream>>>(bufC, W_mu, b_mu, out_mu, Nn, 64, 32, 0);
  gemm_kernel<<<dim3(1, cdiv(Nn, 64)), blk, 0, stream>>>(bufC, W_lv, b_lv, out_lv, Nn, 64, 32, 0);
  bn_stats_kernel<<<256, blk, 0, stream>>>(out_mu, st_mu, 32);
  bn_apply_kernel<<<cdiv((long)Nn * 32, 256), blk, 0, stream>>>(out_mu, out_z, st_mu, g_mu, be_mu, Nn * 32, 31, 32);
  bn_stats_kernel<<<256, blk, 0, stream>>>(out_lv, st_lv, 32);
  bn_apply_kernel<<<cdiv((long)Nn * 32, 256), blk, 0, stream>>>(out_lv, nullptr, st_lv, g_lv, be_lv, Nn * 32, 31, 32);

  // decoder 32 -> 64 -> 128 -> 256 (relu then BN between)
  gemm_kernel<<<dim3(1, cdiv(Nn, 64)), blk, 0, stream>>>(out_z, W_d1, b_d1, bufD, Nn, 32, 64, 1);
  bn_stats_kernel<<<256, blk, 0, stream>>>(bufD, st_d1, 64);
  bn_apply_kernel<<<cdiv((long)Nn * 64, 256), blk, 0, stream>>>(bufD, nullptr, st_d1, g_d1, be_d1, Nn * 64, 63, 64);

  gemm_kernel<<<dim3(2, cdiv(Nn, 64)), blk, 0, stream>>>(bufD, W_d2, b_d2, bufB, Nn, 64, 128, 1);
  bn_stats_kernel<<<256, blk, 0, stream>>>(bufB, st_d2, 128);
  bn_apply_kernel<<<cdiv((long)Nn * 128, 256), blk, 0, stream>>>(bufB, nullptr, st_d2, g_d2, be_d2, Nn * 128, 127, 128);

  gemm_kernel<<<dim3(4, cdiv(Nn, 64)), blk, 0, stream>>>(bufB, W_d3, b_d3, out_xr, Nn, 128, 256, 0);

  // Student-t q
  q_kernel<<<cdiv(Nn, 256), blk, 0, stream>>>(out_z, cent, out_q);
}

// Round 2
// 1538.829 us; speedup vs baseline: 4.0706x; 4.0706x over previous
//
#include <hip/hip_runtime.h>

constexpr int Nn = 100000;
constexpr int Ne = 1600000;
constexpr float BN_EPS = 1e-5f;

// ---------- small utility kernels ----------

__global__ void fill_kernel(float* __restrict__ p, float v, int n) {
  int i = blockIdx.x * blockDim.x + threadIdx.x;
  if (i < n) p[i] = v;
}

__global__ void izero_kernel(int* __restrict__ p, int n) {
  int i = blockIdx.x * blockDim.x + threadIdx.x;
  if (i < n) p[i] = 0;
}

__global__ void deg_accum_kernel(const int* __restrict__ row,
                                 const float* __restrict__ w,
                                 float* __restrict__ deg) {
  int e = blockIdx.x * blockDim.x + threadIdx.x;
  if (e < Ne) atomicAdd(&deg[row[e]], w[e]);
}

__global__ void dinv_kernel(float* __restrict__ d) {
  int i = blockIdx.x * blockDim.x + threadIdx.x;
  if (i < Nn) {
    float v = d[i];
    d[i] = (v > 0.f) ? rsqrtf(fmaxf(v, 1e-12f)) : 0.f;
  }
}

// ---------- CSR build ----------

__global__ void hist_kernel(const int* __restrict__ row, int* __restrict__ cnt) {
  int e = blockIdx.x * blockDim.x + threadIdx.x;
  if (e < Ne) atomicAdd(&cnt[row[e]], 1);
}

// single-block exclusive scan of cnt[Nn] -> rowptr[Nn+1], and off[i]=rowptr[i]
__global__ __launch_bounds__(1024)
void scan_kernel(const int* __restrict__ cnt, int* __restrict__ rowptr,
                 int* __restrict__ off) {
  __shared__ int part[1024];
  int tid = threadIdx.x;
  constexpr int CH = 98;  // 1024*98 = 100352 >= Nn
  int s0 = tid * CH;
  int sum = 0;
  for (int i = 0; i < CH; i++) {
    int idx = s0 + i;
    if (idx < Nn) sum += cnt[idx];
  }
  part[tid] = sum;
  __syncthreads();
  for (int st = 1; st < 1024; st <<= 1) {
    int v = (tid >= st) ? part[tid - st] : 0;
    __syncthreads();
    part[tid] += v;
    __syncthreads();
  }
  int run = (tid == 0) ? 0 : part[tid - 1];
  for (int i = 0; i < CH; i++) {
    int idx = s0 + i;
    if (idx < Nn) {
      rowptr[idx] = run;
      off[idx] = run;
      run += cnt[idx];
    }
  }
  if (tid == 1023) rowptr[Nn] = run;
}

// sorted col + fused norm = dinv[r]*w*dinv[c]
__global__ void csr_fill_kernel(const int* __restrict__ row, const int* __restrict__ col,
                                const float* __restrict__ w, const float* __restrict__ dinv,
                                int* __restrict__ off, int* __restrict__ col_s,
                                float* __restrict__ nrm_s) {
  int e = blockIdx.x * blockDim.x + threadIdx.x;
  if (e < Ne) {
    int r = row[e], c = col[e];
    int p = atomicAdd(&off[r], 1);
    col_s[p] = c;
    nrm_s[p] = dinv[r] * w[e] * dinv[c];
  }
}

// ---------- FP32 tiled GEMM: C[M,Nc] = A[M,K] @ W[K,Nc] (+bias)(relu) ----------

__global__ __launch_bounds__(256)
void gemm_kernel(const float* __restrict__ A, const float* __restrict__ W,
                 const float* __restrict__ bias, float* __restrict__ C,
                 int M, int K, int Nc, int relu) {
  constexpr int BM = 64, BN = 64, BK = 16;
  __shared__ float As[BK][BM + 4];
  __shared__ float Ws[BK][BN];
  int t = threadIdx.x;
  int tx = t & 15, ty = t >> 4;
  int row0 = blockIdx.y * BM, col0 = blockIdx.x * BN;
  float acc[4][4] = {};
  for (int k0 = 0; k0 < K; k0 += BK) {
    {
      int r = t >> 2;
      int kq = (t & 3) << 2;
      int grow = row0 + r;
      float4 a = make_float4(0.f, 0.f, 0.f, 0.f);
      if (grow < M) a = *(const float4*)(A + (size_t)grow * K + (k0 + kq));
      As[kq + 0][r] = a.x; As[kq + 1][r] = a.y;
      As[kq + 2][r] = a.z; As[kq + 3][r] = a.w;
    }
    {
      int r = t >> 4;
      int c = (t & 15) << 2;
      int gc = col0 + c;
      float4 w4 = make_float4(0.f, 0.f, 0.f, 0.f);
      if (gc < Nc) w4 = *(const float4*)(W + (size_t)(k0 + r) * Nc + gc);
      Ws[r][c + 0] = w4.x; Ws[r][c + 1] = w4.y;
      Ws[r][c + 2] = w4.z; Ws[r][c + 3] = w4.w;
    }
    __syncthreads();
#pragma unroll
    for (int kk = 0; kk < BK; kk++) {
      float4 av = *(const float4*)&As[kk][ty << 2];
      float4 wv = *(const float4*)&Ws[kk][tx << 2];
      float a4[4] = {av.x, av.y, av.z, av.w};
      float w4[4] = {wv.x, wv.y, wv.z, wv.w};
#pragma unroll
      for (int i = 0; i < 4; i++)
#pragma unroll
        for (int j = 0; j < 4; j++)
          acc[i][j] += a4[i] * w4[j];
    }
    __syncthreads();
  }
#pragma unroll
  for (int i = 0; i < 4; i++) {
    int grow = row0 + (ty << 2) + i;
    if (grow >= M) continue;
#pragma unroll
    for (int j = 0; j < 4; j++) {
      int gc = col0 + (tx << 2) + j;
      if (gc >= Nc) continue;
      float v = acc[i][j];
      if (bias) v += bias[gc];
      if (relu) v = fmaxf(v, 0.f);
      C[(size_t)grow * Nc + gc] = v;
    }
  }
}

// ---------- gather SpMM: one wave per node ----------
// out[i,:] = relu( dinv[i]^2*t[i,:] + sum_e nrm[e]*t[col[e],:] + bias )

__global__ __launch_bounds__(256)
void gather64_kernel(const float* __restrict__ t, const int* __restrict__ rowptr,
                     const int* __restrict__ col_s, const float* __restrict__ nrm_s,
                     const float* __restrict__ dinv, const float* __restrict__ bias,
                     float* __restrict__ out, int relu) {
  int wave = threadIdx.x >> 6;
  int lane = threadIdx.x & 63;
  int node = blockIdx.x * 4 + wave;
  if (node >= Nn) return;
  int start = rowptr[node], end = rowptr[node + 1];
  float s = dinv[node];
  float acc = s * s * t[(size_t)node * 64 + lane];
  for (int base = start; base < end; base += 64) {
    int m = end - base; if (m > 64) m = 64;
    int cv = 0; float nv = 0.f;
    if (lane < m) { cv = col_s[base + lane]; nv = nrm_s[base + lane]; }
    int k = 0;
    for (; k + 4 <= m; k += 4) {
      int c0 = __shfl(cv, k), c1 = __shfl(cv, k + 1);
      int c2 = __shfl(cv, k + 2), c3 = __shfl(cv, k + 3);
      float n0 = __shfl(nv, k), n1 = __shfl(nv, k + 1);
      float n2 = __shfl(nv, k + 2), n3 = __shfl(nv, k + 3);
      float t0 = t[(size_t)c0 * 64 + lane];
      float t1 = t[(size_t)c1 * 64 + lane];
      float t2 = t[(size_t)c2 * 64 + lane];
      float t3 = t[(size_t)c3 * 64 + lane];
      acc += n0 * t0; acc += n1 * t1; acc += n2 * t2; acc += n3 * t3;
    }
    for (; k < m; k++) {
      int c = __shfl(cv, k);
      float nm = __shfl(nv, k);
      acc += nm * t[(size_t)c * 64 + lane];
    }
  }
  acc += bias[lane];
  if (relu) acc = fmaxf(acc, 0.f);
  out[(size_t)node * 64 + lane] = acc;
}

__global__ __launch_bounds__(256)
void gather128_kernel(const float* __restrict__ t, const int* __restrict__ rowptr,
                      const int* __restrict__ col_s, const float* __restrict__ nrm_s,
                      const float* __restrict__ dinv, const float* __restrict__ bias,
                      float* __restrict__ out, int relu) {
  int wave = threadIdx.x >> 6;
  int lane = threadIdx.x & 63;
  int node = blockIdx.x * 4 + wave;
  if (node >= Nn) return;
  int start = rowptr[node], end = rowptr[node + 1];
  float s = dinv[node];
  float2 ti = ((const float2*)(t + (size_t)node * 128))[lane];
  float ax = s * s * ti.x, ay = s * s * ti.y;
  for (int base = start; base < end; base += 64) {
    int m = end - base; if (m > 64) m = 64;
    int cv = 0; float nv = 0.f;
    if (lane < m) { cv = col_s[base + lane]; nv = nrm_s[base + lane]; }
    int k = 0;
    for (; k + 4 <= m; k += 4) {
      int c0 = __shfl(cv, k), c1 = __shfl(cv, k + 1);
      int c2 = __shfl(cv, k + 2), c3 = __shfl(cv, k + 3);
      float n0 = __shfl(nv, k), n1 = __shfl(nv, k + 1);
      float n2 = __shfl(nv, k + 2), n3 = __shfl(nv, k + 3);
      float2 t0 = ((const float2*)(t + (size_t)c0 * 128))[lane];
      float2 t1 = ((const float2*)(t + (size_t)c1 * 128))[lane];
      float2 t2 = ((const float2*)(t + (size_t)c2 * 128))[lane];
      float2 t3 = ((const float2*)(t + (size_t)c3 * 128))[lane];
      ax += n0 * t0.x; ay += n0 * t0.y;
      ax += n1 * t1.x; ay += n1 * t1.y;
      ax += n2 * t2.x; ay += n2 * t2.y;
      ax += n3 * t3.x; ay += n3 * t3.y;
    }
    for (; k < m; k++) {
      int c = __shfl(cv, k);
      float nm = __shfl(nv, k);
      float2 tv = ((const float2*)(t + (size_t)c * 128))[lane];
      ax += nm * tv.x; ay += nm * tv.y;
    }
  }
  float2 bb = ((const float2*)bias)[lane];
  ax += bb.x; ay += bb.y;
  if (relu) { ax = fmaxf(ax, 0.f); ay = fmaxf(ay, 0.f); }
  ((float2*)(out + (size_t)node * 128))[lane] = make_float2(ax, ay);
}

// ---------- BatchNorm ----------

__global__ __launch_bounds__(256)
void bn_stats_kernel(const float* __restrict__ x, float* __restrict__ stats, int C) {
  __shared__ float ss[256], sq[256];
  int tid = threadIdx.x;
  int col = tid & (C - 1);
  int rgrp = tid / C;
  int rpb = 256 / C;
  float s = 0.f, q = 0.f;
  for (int r = blockIdx.x * rpb + rgrp; r < Nn; r += gridDim.x * rpb) {
    float v = x[(size_t)r * C + col];
    s += v; q += v * v;
  }
  ss[tid] = s; sq[tid] = q;
  __syncthreads();
  for (int st = 128; st >= C; st >>= 1) {
    if (tid < st) { ss[tid] += ss[tid + st]; sq[tid] += sq[tid + st]; }
    __syncthreads();
  }
  if (tid < C) {
    atomicAdd(&stats[tid], ss[tid]);
    atomicAdd(&stats[C + tid], sq[tid]);
  }
}

__global__ void bn_apply_kernel(float* __restrict__ x, float* __restrict__ dup,
                                const float* __restrict__ stats,
                                const float* __restrict__ g, const float* __restrict__ beta,
                                int total, int cmask, int C) {
  int i = blockIdx.x * blockDim.x + threadIdx.x;
  if (i >= total) return;
  int c = i & cmask;
  float m = stats[c] * (1.f / Nn);
  float var = stats[C + c] * (1.f / Nn) - m * m;
  float v = (x[i] - m) * rsqrtf(var + BN_EPS) * g[c] + beta[c];
  x[i] = v;
  if (dup) dup[i] = v;
}

// ---------- Student-t cluster assignment ----------

__global__ __launch_bounds__(256)
void q_kernel(const float* __restrict__ z, const float* __restrict__ centers,
              float* __restrict__ q) {
  __shared__ float cs[50 * 32];
  __shared__ float cn[50];
  int tid = threadIdx.x;
  for (int i = tid; i < 50 * 32; i += 256) cs[i] = centers[i];
  __syncthreads();
  if (tid < 50) {
    float s = 0.f;
    for (int j = 0; j < 32; j++) { float v = cs[tid * 32 + j]; s += v * v; }
    cn[tid] = s;
  }
  __syncthreads();
  int n = blockIdx.x * blockDim.x + tid;
  if (n >= Nn) return;
  float zr[32];
  float zn = 0.f;
  const float4* zp = (const float4*)(z + (size_t)n * 32);
#pragma unroll
  for (int j = 0; j < 8; j++) {
    float4 v = zp[j];
    zr[j * 4 + 0] = v.x; zr[j * 4 + 1] = v.y;
    zr[j * 4 + 2] = v.z; zr[j * 4 + 3] = v.w;
    zn += v.x * v.x + v.y * v.y + v.z * v.z + v.w * v.w;
  }
  float qv[50];
  float qs = 0.f;
  for (int k = 0; k < 50; k++) {
    float dot = 0.f;
#pragma unroll
    for (int j = 0; j < 32; j++) dot += zr[j] * cs[k * 32 + j];
    float d2 = zn + cn[k] - 2.f * dot;
    d2 = fmaxf(d2, 0.f);
    float qq = 1.f / (1.f + d2);
    qv[k] = qq; qs += qq;
  }
  float inv = 1.f / qs;
  float* qo = q + (size_t)n * 50;
  for (int k = 0; k < 50; k++) qo[k] = qv[k] * inv;
}

// ---------- launch ----------

extern "C" void kernel_launch(void* const* d_in, const int* in_sizes, int n_in,
                              void* d_out, int out_size, void* d_ws, size_t ws_size,
                              hipStream_t stream) {
  const float* x     = (const float*)d_in[0];
  const int*   ei    = (const int*)d_in[1];
  const float* ew    = (const float*)d_in[2];
  const float* W_g1  = (const float*)d_in[3];
  const float* b_g1  = (const float*)d_in[4];
  const float* W_g2  = (const float*)d_in[5];
  const float* b_g2  = (const float*)d_in[6];
  const float* W_g3  = (const float*)d_in[7];
  const float* b_g3  = (const float*)d_in[8];
  const float* W_mu  = (const float*)d_in[9];
  const float* b_mu  = (const float*)d_in[10];
  const float* W_lv  = (const float*)d_in[11];
  const float* b_lv  = (const float*)d_in[12];
  const float* g_mu  = (const float*)d_in[13];
  const float* be_mu = (const float*)d_in[14];
  const float* g_lv  = (const float*)d_in[15];
  const float* be_lv = (const float*)d_in[16];
  const float* W_d1  = (const float*)d_in[17];
  const float* b_d1  = (const float*)d_in[18];
  const float* g_d1  = (const float*)d_in[19];
  const float* be_d1 = (const float*)d_in[20];
  const float* W_d2  = (const float*)d_in[21];
  const float* b_d2  = (const float*)d_in[22];
  const float* g_d2  = (const float*)d_in[23];
  const float* be_d2 = (const float*)d_in[24];
  const float* W_d3  = (const float*)d_in[25];
  const float* b_d3  = (const float*)d_in[26];
  const float* cent  = (const float*)d_in[27];

  const int* row = ei;
  const int* col = ei + Ne;

  float* out    = (float*)d_out;
  float* out_z  = out;
  float* out_mu = out + (size_t)Nn * 32;
  float* out_lv = out + (size_t)Nn * 64;
  float* out_xr = out + (size_t)Nn * 96;   // [N,256]
  float* out_q  = out + (size_t)Nn * 352;  // [N,50]

  // workspace layout (~66 MB):
  // dinv[N] | bufB[N*128] | stats[512] | cnt[N] | rowptr[N+1] | off[N] | col_s[E] | nrm_s[E]
  float* ws     = (float*)d_ws;
  float* dinv   = ws;
  float* bufB   = dinv + Nn;
  float* stats  = bufB + (size_t)Nn * 128;
  int*   cnt    = (int*)(stats + 512);
  int*   rowptr = cnt + Nn;
  int*   off    = rowptr + Nn + 1;
  int*   col_s  = off + Nn;
  float* nrm_s  = (float*)(col_s + Ne);
  float* st_mu = stats, *st_lv = stats + 64, *st_d1 = stats + 128, *st_d2 = stats + 256;

  // scratch in the x_recon output region (written last):
  float* bufA = out_xr;                     // [N,128]
  float* bufC = out_xr + (size_t)Nn * 128;  // [N,64]
  float* bufD = out_xr + (size_t)Nn * 192;  // [N,64]

  auto cdiv = [](long a, long b) { return (int)((a + b - 1) / b); };
  dim3 blk(256);

  // degree / dinv
  fill_kernel<<<cdiv(Nn, 256), blk, 0, stream>>>(dinv, 1.0f, Nn);  // self-loop weight
  deg_accum_kernel<<<cdiv(Ne, 256), blk, 0, stream>>>(row, ew, dinv);
  dinv_kernel<<<cdiv(Nn, 256), blk, 0, stream>>>(dinv);
  fill_kernel<<<1, blk, 0, stream>>>(stats, 0.f, 512);

  // CSR build (col_s / nrm_s sorted by row)
  izero_kernel<<<cdiv(Nn, 256), blk, 0, stream>>>(cnt, Nn);
  hist_kernel<<<cdiv(Ne, 256), blk, 0, stream>>>(row, cnt);
  scan_kernel<<<1, 1024, 0, stream>>>(cnt, rowptr, off);
  csr_fill_kernel<<<cdiv(Ne, 256), blk, 0, stream>>>(row, col, ew, dinv, off, col_s, nrm_s);

  int ggrid = cdiv(Nn, 4);  // one wave per node, 4 waves/block

  // GCN layer 1: 256 -> 128, relu
  gemm_kernel<<<dim3(2, cdiv(Nn, 64)), blk, 0, stream>>>(x, W_g1, nullptr, bufA, Nn, 256, 128, 0);
  gather128_kernel<<<ggrid, blk, 0, stream>>>(bufA, rowptr, col_s, nrm_s, dinv, b_g1, bufB, 1);

  // GCN layer 2: 128 -> 64, relu
  gemm_kernel<<<dim3(1, cdiv(Nn, 64)), blk, 0, stream>>>(bufB, W_g2, nullptr, bufC, Nn, 128, 64, 0);
  gather64_kernel<<<ggrid, blk, 0, stream>>>(bufC, rowptr, col_s, nrm_s, dinv, b_g2, bufD, 1);

  // GCN layer 3: 64 -> 64, no relu
  gemm_kernel<<<dim3(1, cdiv(Nn, 64)), blk, 0, stream>>>(bufD, W_g3, nullptr, bufA, Nn, 64, 64, 0);
  gather64_kernel<<<ggrid, blk, 0, stream>>>(bufA, rowptr, col_s, nrm_s, dinv, b_g3, bufC, 0);

  // VAE heads: 64 -> 32 (+BN); z = mu
  gemm_kernel<<<dim3(1, cdiv(Nn, 64)), blk, 0, stream>>>(bufC, W_mu, b_mu, out_mu, Nn, 64, 32, 0);
  gemm_kernel<<<dim3(1, cdiv(Nn, 64)), blk, 0, stream>>>(bufC, W_lv, b_lv, out_lv, Nn, 64, 32, 0);
  bn_stats_kernel<<<256, blk, 0, stream>>>(out_mu, st_mu, 32);
  bn_apply_kernel<<<cdiv((long)Nn * 32, 256), blk, 0, stream>>>(out_mu, out_z, st_mu, g_mu, be_mu, Nn * 32, 31, 32);
  bn_stats_kernel<<<256, blk, 0, stream>>>(out_lv, st_lv, 32);
  bn_apply_kernel<<<cdiv((long)Nn * 32, 256), blk, 0, stream>>>(out_lv, nullptr, st_lv, g_lv, be_lv, Nn * 32, 31, 32);

  // decoder 32 -> 64 -> 128 -> 256
  gemm_kernel<<<dim3(1, cdiv(Nn, 64)), blk, 0, stream>>>(out_z, W_d1, b_d1, bufD, Nn, 32, 64, 1);
  bn_stats_kernel<<<256, blk, 0, stream>>>(bufD, st_d1, 64);
  bn_apply_kernel<<<cdiv((long)Nn * 64, 256), blk, 0, stream>>>(bufD, nullptr, st_d1, g_d1, be_d1, Nn * 64, 63, 64);

  gemm_kernel<<<dim3(2, cdiv(Nn, 64)), blk, 0, stream>>>(bufD, W_d2, b_d2, bufB, Nn, 64, 128, 1);
  bn_stats_kernel<<<256, blk, 0, stream>>>(bufB, st_d2, 128);
  bn_apply_kernel<<<cdiv((long)Nn * 128, 256), blk, 0, stream>>>(bufB, nullptr, st_d2, g_d2, be_d2, Nn * 128, 127, 128);

  gemm_kernel<<<dim3(4, cdiv(Nn, 64)), blk, 0, stream>>>(bufB, W_d3, b_d3, out_xr, Nn, 128, 256, 0);

  // Student-t q
  q_kernel<<<cdiv(Nn, 256), blk, 0, stream>>>(out_z, cent, out_q);
}

// Round 3
// 1282.537 us; speedup vs baseline: 4.8840x; 1.1998x over previous
//
#include <hip/hip_runtime.h>

constexpr int Nn = 100000;
constexpr int Ne = 1600000;
constexpr float BN_EPS = 1e-5f;

constexpr int SCAN_TILE = 1024;                          // elements per block
constexpr int SCAN_NB = (Nn + SCAN_TILE - 1) / SCAN_TILE; // 98

// ---------- small utility kernels ----------

__global__ void fill_kernel(float* __restrict__ p, float v, int n) {
  int i = blockIdx.x * blockDim.x + threadIdx.x;
  if (i < n) p[i] = v;
}

__global__ void izero_kernel(int* __restrict__ p, int n) {
  int i = blockIdx.x * blockDim.x + threadIdx.x;
  if (i < n) p[i] = 0;
}

// fused: deg[r]+=w  and  cnt[r]+=1  (one pass over edges)
__global__ void deg_hist_kernel(const int* __restrict__ row,
                                const float* __restrict__ w,
                                float* __restrict__ deg, int* __restrict__ cnt) {
  int e = blockIdx.x * blockDim.x + threadIdx.x;
  if (e < Ne) {
    int r = row[e];
    atomicAdd(&deg[r], w[e]);
    atomicAdd(&cnt[r], 1);
  }
}

__global__ void dinv_kernel(float* __restrict__ d) {
  int i = blockIdx.x * blockDim.x + threadIdx.x;
  if (i < Nn) {
    float v = d[i];
    d[i] = (v > 0.f) ? rsqrtf(fmaxf(v, 1e-12f)) : 0.f;
  }
}

// ---------- multi-block exclusive scan (cnt[Nn] -> rowptr[Nn+1], off) ----------

__global__ __launch_bounds__(256)
void scan_phase1(const int* __restrict__ cnt, int* __restrict__ bsum) {
  __shared__ int s[256];
  int b = blockIdx.x, tid = threadIdx.x;
  int base = b * SCAN_TILE + tid * 4;
  int t = 0;
#pragma unroll
  for (int i = 0; i < 4; i++) {
    int idx = base + i;
    if (idx < Nn) t += cnt[idx];
  }
  s[tid] = t;
  __syncthreads();
  for (int st = 128; st > 0; st >>= 1) {
    if (tid < st) s[tid] += s[tid + st];
    __syncthreads();
  }
  if (tid == 0) bsum[b] = s[0];
}

__global__ __launch_bounds__(128)
void scan_phase2(int* __restrict__ bsum) {  // in-place exclusive scan, SCAN_NB <= 128
  __shared__ int s[128];
  int tid = threadIdx.x;
  int v = (tid < SCAN_NB) ? bsum[tid] : 0;
  s[tid] = v;
  __syncthreads();
  for (int st = 1; st < 128; st <<= 1) {
    int u = (tid >= st) ? s[tid - st] : 0;
    __syncthreads();
    s[tid] += u;
    __syncthreads();
  }
  if (tid < SCAN_NB) bsum[tid] = s[tid] - v;  // exclusive prefix
}

__global__ __launch_bounds__(256)
void scan_phase3(const int* __restrict__ cnt, const int* __restrict__ bsum,
                 int* __restrict__ rowptr, int* __restrict__ off) {
  __shared__ int s[256];
  int b = blockIdx.x, tid = threadIdx.x;
  int base = b * SCAN_TILE + tid * 4;
  int vals[4];
  int t = 0;
#pragma unroll
  for (int i = 0; i < 4; i++) {
    int idx = base + i;
    vals[i] = (idx < Nn) ? cnt[idx] : 0;
    t += vals[i];
  }
  s[tid] = t;
  __syncthreads();
  for (int st = 1; st < 256; st <<= 1) {
    int u = (tid >= st) ? s[tid - st] : 0;
    __syncthreads();
    s[tid] += u;
    __syncthreads();
  }
  int run = bsum[b] + s[tid] - t;  // exclusive prefix for this thread's 4 elems
#pragma unroll
  for (int i = 0; i < 4; i++) {
    int idx = base + i;
    if (idx < Nn) { rowptr[idx] = run; off[idx] = run; run += vals[i]; }
  }
  if (b == SCAN_NB - 1 && tid == 255) rowptr[Nn] = bsum[b] + s[255];
}

// sorted col + fused norm = dinv[r]*w*dinv[c]
__global__ void csr_fill_kernel(const int* __restrict__ row, const int* __restrict__ col,
                                const float* __restrict__ w, const float* __restrict__ dinv,
                                int* __restrict__ off, int* __restrict__ col_s,
                                float* __restrict__ nrm_s) {
  int e = blockIdx.x * blockDim.x + threadIdx.x;
  if (e < Ne) {
    int r = row[e], c = col[e];
    int p = atomicAdd(&off[r], 1);
    col_s[p] = c;
    nrm_s[p] = dinv[r] * w[e] * dinv[c];
  }
}

// ---------- FP32 tiled GEMM: C[M,Nc] = A[M,K] @ W[K,Nc] (+bias)(relu) ----------

__global__ __launch_bounds__(256)
void gemm_kernel(const float* __restrict__ A, const float* __restrict__ W,
                 const float* __restrict__ bias, float* __restrict__ C,
                 int M, int K, int Nc, int relu) {
  constexpr int BM = 64, BN = 64, BK = 16;
  __shared__ float As[BK][BM + 4];
  __shared__ float Ws[BK][BN];
  int t = threadIdx.x;
  int tx = t & 15, ty = t >> 4;
  int row0 = blockIdx.y * BM, col0 = blockIdx.x * BN;
  float acc[4][4] = {};
  for (int k0 = 0; k0 < K; k0 += BK) {
    {
      int r = t >> 2;
      int kq = (t & 3) << 2;
      int grow = row0 + r;
      float4 a = make_float4(0.f, 0.f, 0.f, 0.f);
      if (grow < M) a = *(const float4*)(A + (size_t)grow * K + (k0 + kq));
      As[kq + 0][r] = a.x; As[kq + 1][r] = a.y;
      As[kq + 2][r] = a.z; As[kq + 3][r] = a.w;
    }
    {
      int r = t >> 4;
      int c = (t & 15) << 2;
      int gc = col0 + c;
      float4 w4 = make_float4(0.f, 0.f, 0.f, 0.f);
      if (gc < Nc) w4 = *(const float4*)(W + (size_t)(k0 + r) * Nc + gc);
      Ws[r][c + 0] = w4.x; Ws[r][c + 1] = w4.y;
      Ws[r][c + 2] = w4.z; Ws[r][c + 3] = w4.w;
    }
    __syncthreads();
#pragma unroll
    for (int kk = 0; kk < BK; kk++) {
      float4 av = *(const float4*)&As[kk][ty << 2];
      float4 wv = *(const float4*)&Ws[kk][tx << 2];
      float a4[4] = {av.x, av.y, av.z, av.w};
      float w4[4] = {wv.x, wv.y, wv.z, wv.w};
#pragma unroll
      for (int i = 0; i < 4; i++)
#pragma unroll
        for (int j = 0; j < 4; j++)
          acc[i][j] += a4[i] * w4[j];
    }
    __syncthreads();
  }
#pragma unroll
  for (int i = 0; i < 4; i++) {
    int grow = row0 + (ty << 2) + i;
    if (grow >= M) continue;
#pragma unroll
    for (int j = 0; j < 4; j++) {
      int gc = col0 + (tx << 2) + j;
      if (gc >= Nc) continue;
      float v = acc[i][j];
      if (bias) v += bias[gc];
      if (relu) v = fmaxf(v, 0.f);
      C[(size_t)grow * Nc + gc] = v;
    }
  }
}

// ---------- gather SpMM: one wave per node ----------

__global__ __launch_bounds__(256)
void gather64_kernel(const float* __restrict__ t, const int* __restrict__ rowptr,
                     const int* __restrict__ col_s, const float* __restrict__ nrm_s,
                     const float* __restrict__ dinv, const float* __restrict__ bias,
                     float* __restrict__ out, int relu) {
  int wave = threadIdx.x >> 6;
  int lane = threadIdx.x & 63;
  int node = blockIdx.x * 4 + wave;
  if (node >= Nn) return;
  int start = rowptr[node], end = rowptr[node + 1];
  float s = dinv[node];
  float acc = s * s * t[(size_t)node * 64 + lane];
  for (int base = start; base < end; base += 64) {
    int m = end - base; if (m > 64) m = 64;
    int cv = 0; float nv = 0.f;
    if (lane < m) { cv = col_s[base + lane]; nv = nrm_s[base + lane]; }
    int k = 0;
    for (; k + 4 <= m; k += 4) {
      int c0 = __shfl(cv, k), c1 = __shfl(cv, k + 1);
      int c2 = __shfl(cv, k + 2), c3 = __shfl(cv, k + 3);
      float n0 = __shfl(nv, k), n1 = __shfl(nv, k + 1);
      float n2 = __shfl(nv, k + 2), n3 = __shfl(nv, k + 3);
      float t0 = t[(size_t)c0 * 64 + lane];
      float t1 = t[(size_t)c1 * 64 + lane];
      float t2 = t[(size_t)c2 * 64 + lane];
      float t3 = t[(size_t)c3 * 64 + lane];
      acc += n0 * t0; acc += n1 * t1; acc += n2 * t2; acc += n3 * t3;
    }
    for (; k < m; k++) {
      int c = __shfl(cv, k);
      float nm = __shfl(nv, k);
      acc += nm * t[(size_t)c * 64 + lane];
    }
  }
  acc += bias[lane];
  if (relu) acc = fmaxf(acc, 0.f);
  out[(size_t)node * 64 + lane] = acc;
}

__global__ __launch_bounds__(256)
void gather128_kernel(const float* __restrict__ t, const int* __restrict__ rowptr,
                      const int* __restrict__ col_s, const float* __restrict__ nrm_s,
                      const float* __restrict__ dinv, const float* __restrict__ bias,
                      float* __restrict__ out, int relu) {
  int wave = threadIdx.x >> 6;
  int lane = threadIdx.x & 63;
  int node = blockIdx.x * 4 + wave;
  if (node >= Nn) return;
  int start = rowptr[node], end = rowptr[node + 1];
  float s = dinv[node];
  float2 ti = ((const float2*)(t + (size_t)node * 128))[lane];
  float ax = s * s * ti.x, ay = s * s * ti.y;
  for (int base = start; base < end; base += 64) {
    int m = end - base; if (m > 64) m = 64;
    int cv = 0; float nv = 0.f;
    if (lane < m) { cv = col_s[base + lane]; nv = nrm_s[base + lane]; }
    int k = 0;
    for (; k + 4 <= m; k += 4) {
      int c0 = __shfl(cv, k), c1 = __shfl(cv, k + 1);
      int c2 = __shfl(cv, k + 2), c3 = __shfl(cv, k + 3);
      float n0 = __shfl(nv, k), n1 = __shfl(nv, k + 1);
      float n2 = __shfl(nv, k + 2), n3 = __shfl(nv, k + 3);
      float2 t0 = ((const float2*)(t + (size_t)c0 * 128))[lane];
      float2 t1 = ((const float2*)(t + (size_t)c1 * 128))[lane];
      float2 t2 = ((const float2*)(t + (size_t)c2 * 128))[lane];
      float2 t3 = ((const float2*)(t + (size_t)c3 * 128))[lane];
      ax += n0 * t0.x; ay += n0 * t0.y;
      ax += n1 * t1.x; ay += n1 * t1.y;
      ax += n2 * t2.x; ay += n2 * t2.y;
      ax += n3 * t3.x; ay += n3 * t3.y;
    }
    for (; k < m; k++) {
      int c = __shfl(cv, k);
      float nm = __shfl(nv, k);
      float2 tv = ((const float2*)(t + (size_t)c * 128))[lane];
      ax += nm * tv.x; ay += nm * tv.y;
    }
  }
  float2 bb = ((const float2*)bias)[lane];
  ax += bb.x; ay += bb.y;
  if (relu) { ax = fmaxf(ax, 0.f); ay = fmaxf(ay, 0.f); }
  ((float2*)(out + (size_t)node * 128))[lane] = make_float2(ax, ay);
}

// ---------- BatchNorm ----------

__global__ __launch_bounds__(256)
void bn_stats_kernel(const float* __restrict__ x, float* __restrict__ stats, int C) {
  __shared__ float ss[256], sq[256];
  int tid = threadIdx.x;
  int col = tid & (C - 1);
  int rgrp = tid / C;
  int rpb = 256 / C;
  float s = 0.f, q = 0.f;
  for (int r = blockIdx.x * rpb + rgrp; r < Nn; r += gridDim.x * rpb) {
    float v = x[(size_t)r * C + col];
    s += v; q += v * v;
  }
  ss[tid] = s; sq[tid] = q;
  __syncthreads();
  for (int st = 128; st >= C; st >>= 1) {
    if (tid < st) { ss[tid] += ss[tid + st]; sq[tid] += sq[tid + st]; }
    __syncthreads();
  }
  if (tid < C) {
    atomicAdd(&stats[tid], ss[tid]);
    atomicAdd(&stats[C + tid], sq[tid]);
  }
}

__global__ void bn_apply_kernel(float* __restrict__ x, float* __restrict__ dup,
                                const float* __restrict__ stats,
                                const float* __restrict__ g, const float* __restrict__ beta,
                                int total, int cmask, int C) {
  int i = blockIdx.x * blockDim.x + threadIdx.x;
  if (i >= total) return;
  int c = i & cmask;
  float m = stats[c] * (1.f / Nn);
  float var = stats[C + c] * (1.f / Nn) - m * m;
  float v = (x[i] - m) * rsqrtf(var + BN_EPS) * g[c] + beta[c];
  x[i] = v;
  if (dup) dup[i] = v;
}

// ---------- Student-t cluster assignment ----------

__global__ __launch_bounds__(256)
void q_kernel(const float* __restrict__ z, const float* __restrict__ centers,
              float* __restrict__ q) {
  __shared__ float cs[50 * 32];
  __shared__ float cn[50];
  int tid = threadIdx.x;
  for (int i = tid; i < 50 * 32; i += 256) cs[i] = centers[i];
  __syncthreads();
  if (tid < 50) {
    float s = 0.f;
    for (int j = 0; j < 32; j++) { float v = cs[tid * 32 + j]; s += v * v; }
    cn[tid] = s;
  }
  __syncthreads();
  int n = blockIdx.x * blockDim.x + tid;
  if (n >= Nn) return;
  float zr[32];
  float zn = 0.f;
  const float4* zp = (const float4*)(z + (size_t)n * 32);
#pragma unroll
  for (int j = 0; j < 8; j++) {
    float4 v = zp[j];
    zr[j * 4 + 0] = v.x; zr[j * 4 + 1] = v.y;
    zr[j * 4 + 2] = v.z; zr[j * 4 + 3] = v.w;
    zn += v.x * v.x + v.y * v.y + v.z * v.z + v.w * v.w;
  }
  float qv[50];
  float qs = 0.f;
  for (int k = 0; k < 50; k++) {
    float dot = 0.f;
#pragma unroll
    for (int j = 0; j < 32; j++) dot += zr[j] * cs[k * 32 + j];
    float d2 = zn + cn[k] - 2.f * dot;
    d2 = fmaxf(d2, 0.f);
    float qq = 1.f / (1.f + d2);
    qv[k] = qq; qs += qq;
  }
  float inv = 1.f / qs;
  float* qo = q + (size_t)n * 50;
  for (int k = 0; k < 50; k++) qo[k] = qv[k] * inv;
}

// ---------- launch ----------

extern "C" void kernel_launch(void* const* d_in, const int* in_sizes, int n_in,
                              void* d_out, int out_size, void* d_ws, size_t ws_size,
                              hipStream_t stream) {
  const float* x     = (const float*)d_in[0];
  const int*   ei    = (const int*)d_in[1];
  const float* ew    = (const float*)d_in[2];
  const float* W_g1  = (const float*)d_in[3];
  const float* b_g1  = (const float*)d_in[4];
  const float* W_g2  = (const float*)d_in[5];
  const float* b_g2  = (const float*)d_in[6];
  const float* W_g3  = (const float*)d_in[7];
  const float* b_g3  = (const float*)d_in[8];
  const float* W_mu  = (const float*)d_in[9];
  const float* b_mu  = (const float*)d_in[10];
  const float* W_lv  = (const float*)d_in[11];
  const float* b_lv  = (const float*)d_in[12];
  const float* g_mu  = (const float*)d_in[13];
  const float* be_mu = (const float*)d_in[14];
  const float* g_lv  = (const float*)d_in[15];
  const float* be_lv = (const float*)d_in[16];
  const float* W_d1  = (const float*)d_in[17];
  const float* b_d1  = (const float*)d_in[18];
  const float* g_d1  = (const float*)d_in[19];
  const float* be_d1 = (const float*)d_in[20];
  const float* W_d2  = (const float*)d_in[21];
  const float* b_d2  = (const float*)d_in[22];
  const float* g_d2  = (const float*)d_in[23];
  const float* be_d2 = (const float*)d_in[24];
  const float* W_d3  = (const float*)d_in[25];
  const float* b_d3  = (const float*)d_in[26];
  const float* cent  = (const float*)d_in[27];

  const int* row = ei;
  const int* col = ei + Ne;

  float* out    = (float*)d_out;
  float* out_z  = out;
  float* out_mu = out + (size_t)Nn * 32;
  float* out_lv = out + (size_t)Nn * 64;
  float* out_xr = out + (size_t)Nn * 96;   // [N,256]
  float* out_q  = out + (size_t)Nn * 352;  // [N,50]

  // workspace layout (~66 MB):
  // dinv[N] | bufB[N*128] | stats[512] | cnt[N] | rowptr[N+1] | off[N] | bsum[NB] | col_s[E] | nrm_s[E]
  float* ws     = (float*)d_ws;
  float* dinv   = ws;
  float* bufB   = dinv + Nn;
  float* stats  = bufB + (size_t)Nn * 128;
  int*   cnt    = (int*)(stats + 512);
  int*   rowptr = cnt + Nn;
  int*   off    = rowptr + Nn + 1;
  int*   bsum   = off + Nn;
  int*   col_s  = bsum + 128;
  float* nrm_s  = (float*)(col_s + Ne);
  float* st_mu = stats, *st_lv = stats + 64, *st_d1 = stats + 128, *st_d2 = stats + 256;

  // scratch in the x_recon output region (written last):
  float* bufA = out_xr;                     // [N,128]
  float* bufC = out_xr + (size_t)Nn * 128;  // [N,64]
  float* bufD = out_xr + (size_t)Nn * 192;  // [N,64]

  auto cdiv = [](long a, long b) { return (int)((a + b - 1) / b); };
  dim3 blk(256);

  // degree + histogram (fused single edge pass)
  fill_kernel<<<cdiv(Nn, 256), blk, 0, stream>>>(dinv, 1.0f, Nn);  // self-loop weight
  izero_kernel<<<cdiv(Nn, 256), blk, 0, stream>>>(cnt, Nn);
  fill_kernel<<<1, blk, 0, stream>>>(stats, 0.f, 512);
  deg_hist_kernel<<<cdiv(Ne, 256), blk, 0, stream>>>(row, ew, dinv, cnt);
  dinv_kernel<<<cdiv(Nn, 256), blk, 0, stream>>>(dinv);

  // CSR build: multi-block scan then fill
  scan_phase1<<<SCAN_NB, blk, 0, stream>>>(cnt, bsum);
  scan_phase2<<<1, 128, 0, stream>>>(bsum);
  scan_phase3<<<SCAN_NB, blk, 0, stream>>>(cnt, bsum, rowptr, off);
  csr_fill_kernel<<<cdiv(Ne, 256), blk, 0, stream>>>(row, col, ew, dinv, off, col_s, nrm_s);

  int ggrid = cdiv(Nn, 4);  // one wave per node, 4 waves/block

  // GCN layer 1: 256 -> 128, relu
  gemm_kernel<<<dim3(2, cdiv(Nn, 64)), blk, 0, stream>>>(x, W_g1, nullptr, bufA, Nn, 256, 128, 0);
  gather128_kernel<<<ggrid, blk, 0, stream>>>(bufA, rowptr, col_s, nrm_s, dinv, b_g1, bufB, 1);

  // GCN layer 2: 128 -> 64, relu
  gemm_kernel<<<dim3(1, cdiv(Nn, 64)), blk, 0, stream>>>(bufB, W_g2, nullptr, bufC, Nn, 128, 64, 0);
  gather64_kernel<<<ggrid, blk, 0, stream>>>(bufC, rowptr, col_s, nrm_s, dinv, b_g2, bufD, 1);

  // GCN layer 3: 64 -> 64, no relu
  gemm_kernel<<<dim3(1, cdiv(Nn, 64)), blk, 0, stream>>>(bufD, W_g3, nullptr, bufA, Nn, 64, 64, 0);
  gather64_kernel<<<ggrid, blk, 0, stream>>>(bufA, rowptr, col_s, nrm_s, dinv, b_g3, bufC, 0);

  // VAE heads: 64 -> 32 (+BN); z = mu
  gemm_kernel<<<dim3(1, cdiv(Nn, 64)), blk, 0, stream>>>(bufC, W_mu, b_mu, out_mu, Nn, 64, 32, 0);
  gemm_kernel<<<dim3(1, cdiv(Nn, 64)), blk, 0, stream>>>(bufC, W_lv, b_lv, out_lv, Nn, 64, 32, 0);
  bn_stats_kernel<<<256, blk, 0, stream>>>(out_mu, st_mu, 32);
  bn_apply_kernel<<<cdiv((long)Nn * 32, 256), blk, 0, stream>>>(out_mu, out_z, st_mu, g_mu, be_mu, Nn * 32, 31, 32);
  bn_stats_kernel<<<256, blk, 0, stream>>>(out_lv, st_lv, 32);
  bn_apply_kernel<<<cdiv((long)Nn * 32, 256), blk, 0, stream>>>(out_lv, nullptr, st_lv, g_lv, be_lv, Nn * 32, 31, 32);

  // decoder 32 -> 64 -> 128 -> 256
  gemm_kernel<<<dim3(1, cdiv(Nn, 64)), blk, 0, stream>>>(out_z, W_d1, b_d1, bufD, Nn, 32, 64, 1);
  bn_stats_kernel<<<256, blk, 0, stream>>>(bufD, st_d1, 64);
  bn_apply_kernel<<<cdiv((long)Nn * 64, 256), blk, 0, stream>>>(bufD, nullptr, st_d1, g_d1, be_d1, Nn * 64, 63, 64);

  gemm_kernel<<<dim3(2, cdiv(Nn, 64)), blk, 0, stream>>>(bufD, W_d2, b_d2, bufB, Nn, 64, 128, 1);
  bn_stats_kernel<<<256, blk, 0, stream>>>(bufB, st_d2, 128);
  bn_apply_kernel<<<cdiv((long)Nn * 128, 256), blk, 0, stream>>>(bufB, nullptr, st_d2, g_d2, be_d2, Nn * 128, 127, 128);

  gemm_kernel<<<dim3(4, cdiv(Nn, 64)), blk, 0, stream>>>(bufB, W_d3, b_d3, out_xr, Nn, 128, 256, 0);

  // Student-t q
  q_kernel<<<cdiv(Nn, 256), blk, 0, stream>>>(out_z, cent, out_q);
}